// Round 2
// baseline (588.243 us; speedup 1.0000x reference)
//
#include <hip/hip_runtime.h>
#include <hip/hip_bf16.h>
#include <stdint.h>

#define S 8192
#define D 512
#define SCALE 0.044194173824159216f  // 1/sqrt(512)
#define KZ 4
#define NEG_BIG -1e30f

typedef __attribute__((ext_vector_type(8))) short short8;
typedef __attribute__((ext_vector_type(4))) float f32x4;

__device__ inline unsigned short f32_to_bf16(float f) {
    union { float f; uint32_t u; } v; v.f = f;
    uint32_t u = v.u;
    uint32_t r = (u + 0x7FFFu + ((u >> 16) & 1u)) >> 16;
    return (unsigned short)r;
}

__device__ inline uint2 pack4(float4 v) {
    uint2 p;
    p.x = (uint32_t)f32_to_bf16(v.x) | ((uint32_t)f32_to_bf16(v.y) << 16);
    p.y = (uint32_t)f32_to_bf16(v.z) | ((uint32_t)f32_to_bf16(v.w) << 16);
    return p;
}

// async global->LDS, 16B per lane; lds base must be wave-uniform
__device__ inline void gload16(const void* g, void* l) {
    __builtin_amdgcn_global_load_lds(
        (const __attribute__((address_space(1))) unsigned int*)g,
        (__attribute__((address_space(3))) unsigned int*)l, 16, 0, 0);
}

// stage a (32*W)x32 bf16 tile (W = nthreads/64 waves) from row-major src into
// linear LDS [rows][32]; per wave 2 calls x 64 lanes x 16B.
__device__ inline void stage_g2l(const short* __restrict__ src, int ld, short* dst, int t) {
    int w = t >> 6, l = t & 63;
    int lr = l >> 2, lc = (l & 3) * 8;
#pragma unroll
    for (int j = 0; j < 2; j++) {
        int row = (w << 5) + (j << 4) + lr;
        gload16(src + (size_t)row * ld + lc, dst + (w << 10) + (j << 9));
    }
}

__device__ inline void mfma_tile(const short* As, const short* Bs,
                                 f32x4 acc[4][4], int wr, int wc, int lane) {
    int rl = lane & 15;
    int kg = lane >> 4;
    short8 a[4], b[4];
#pragma unroll
    for (int m = 0; m < 4; m++)
        a[m] = *reinterpret_cast<const short8*>(&As[(wr * 64 + m * 16 + rl) * 32 + kg * 8]);
#pragma unroll
    for (int n = 0; n < 4; n++)
        b[n] = *reinterpret_cast<const short8*>(&Bs[(wc * 64 + n * 16 + rl) * 32 + kg * 8]);
#pragma unroll
    for (int m = 0; m < 4; m++)
#pragma unroll
        for (int n = 0; n < 4; n++)
            acc[m][n] = __builtin_amdgcn_mfma_f32_16x16x32_bf16(a[m], b[n], acc[m][n], 0, 0, 0);
}

// ---------------- convert fp32 inputs to bf16 ----------------
__global__ __launch_bounds__(256) void k_convert(
    const float* __restrict__ x, const float* __restrict__ Wq,
    const float* __restrict__ Wk, const float* __restrict__ Wv,
    short* __restrict__ xb, short* __restrict__ Wb) {
    size_t i4 = (size_t)blockIdx.x * 256 + threadIdx.x;
    const size_t XN4 = (size_t)S * D / 4;
    if (i4 < XN4) {
        float4 v = reinterpret_cast<const float4*>(x)[i4];
        reinterpret_cast<uint2*>(xb)[i4] = pack4(v);
    } else {
        size_t j4 = i4 - XN4;
        size_t w = j4 >> 16;
        size_t rem = j4 & 65535;
        const float* src = (w == 0) ? Wq : ((w == 1) ? Wk : Wv);
        float4 v = reinterpret_cast<const float4*>(src)[rem];
        reinterpret_cast<uint2*>(Wb)[j4] = pack4(v);
    }
}

// ---------------- QKV projection ----------------
__global__ __launch_bounds__(256) void k_qkv(
    const short* __restrict__ xb, const short* __restrict__ Wb,
    const float* __restrict__ bq, const float* __restrict__ bk,
    const float* __restrict__ bv, short* __restrict__ QKV) {
    __shared__ __align__(16) short As[128 * 32], Bs[128 * 32];
    int which = blockIdx.z;
    const short* W = Wb + (size_t)which * D * D;
    const float* bias = (which == 0) ? bq : ((which == 1) ? bk : bv);
    short* out = QKV + (size_t)which * S * D;
    int r0 = blockIdx.x * 128, c0 = blockIdx.y * 128;
    int t = threadIdx.x, lane = t & 63, w = t >> 6, wr = w >> 1, wc = w & 1;
    f32x4 acc[4][4];
#pragma unroll
    for (int m = 0; m < 4; m++)
#pragma unroll
        for (int n = 0; n < 4; n++)
#pragma unroll
            for (int j = 0; j < 4; j++) acc[m][n][j] = 0.0f;

    for (int kk = 0; kk < D; kk += 32) {
        __syncthreads();
        stage_g2l(xb + (size_t)r0 * D + kk, D, As, t);
        stage_g2l(W + (size_t)c0 * D + kk, D, Bs, t);
        __syncthreads();
        mfma_tile(As, Bs, acc, wr, wc, lane);
    }
    int rg = lane >> 4, cl = lane & 15;
#pragma unroll
    for (int m = 0; m < 4; m++)
#pragma unroll
        for (int n = 0; n < 4; n++) {
            int col = c0 + wc * 64 + n * 16 + cl;
            float b = bias[col];
#pragma unroll
            for (int j = 0; j < 4; j++) {
                int row = r0 + wr * 64 + m * 16 + rg * 4 + j;
                out[(size_t)row * D + col] = (short)f32_to_bf16(acc[m][n][j] + b);
            }
        }
}

// ---------------- V transpose ----------------
__global__ __launch_bounds__(256) void k_transpose(const short* __restrict__ V,
                                                   short* __restrict__ Vt) {
    __shared__ short tile[64][65];
    int r0 = blockIdx.x * 64;
    int c0 = blockIdx.y * 64;
    int t = threadIdx.x;
#pragma unroll
    for (int j = 0; j < 16; j++) {
        int idx = t + j * 256;
        int r = idx >> 6, c = idx & 63;
        tile[r][c] = V[(size_t)(r0 + r) * D + c0 + c];
    }
    __syncthreads();
#pragma unroll
    for (int j = 0; j < 16; j++) {
        int idx = t + j * 256;
        int rr = idx >> 6, cc = idx & 63;
        Vt[(size_t)(c0 + rr) * S + r0 + cc] = tile[cc][rr];
    }
}

// ---------------- scores: raw = mask(QK^T*scale); per-tile row max/sumexp partials ----------------
__global__ __launch_bounds__(256) void k_scores(const short* __restrict__ Qb,
                                                const short* __restrict__ Kb,
                                                float* __restrict__ raw,
                                                float* __restrict__ attn,
                                                float* __restrict__ pm,
                                                float* __restrict__ pl) {
    int bj = blockIdx.x, bi = blockIdx.y;
    int r0 = bi * 128, c0 = bj * 128;
    int t = threadIdx.x;
    if (bj > bi) {  // strictly-upper tile: final attn is zero
#pragma unroll
        for (int j = 0; j < 16; j++) {
            int c = t + j * 256;
            int r = c >> 5;
            int c4 = (c & 31) * 4;
            *reinterpret_cast<float4*>(&attn[(size_t)(r0 + r) * S + c0 + c4]) =
                make_float4(0.f, 0.f, 0.f, 0.f);
        }
        return;
    }
    __shared__ __align__(16) short As[128 * 32], Bs[128 * 32];
    __shared__ float wred[2][128], wsum[2][128];
    int lane = t & 63, w = t >> 6, wr = w >> 1, wc = w & 1;
    f32x4 acc[4][4];
#pragma unroll
    for (int m = 0; m < 4; m++)
#pragma unroll
        for (int n = 0; n < 4; n++)
#pragma unroll
            for (int j = 0; j < 4; j++) acc[m][n][j] = 0.0f;

    for (int kk = 0; kk < D; kk += 32) {
        __syncthreads();
        stage_g2l(Qb + (size_t)r0 * D + kk, D, As, t);
        stage_g2l(Kb + (size_t)c0 * D + kk, D, Bs, t);
        __syncthreads();
        mfma_tile(As, Bs, acc, wr, wc, lane);
    }
    int rg = lane >> 4, cl = lane & 15;
    bool diag = (bi == bj);
    // scale + causal mask in place
#pragma unroll
    for (int m = 0; m < 4; m++)
#pragma unroll
        for (int n = 0; n < 4; n++)
#pragma unroll
            for (int jj = 0; jj < 4; jj++) {
                int row = wr * 64 + m * 16 + rg * 4 + jj;
                int col = wc * 64 + n * 16 + cl;
                float v = acc[m][n][jj] * SCALE;
                if (diag && col > row) v = NEG_BIG;
                acc[m][n][jj] = v;
            }
    // per-row max over this tile's 128 cols
#pragma unroll
    for (int m = 0; m < 4; m++)
#pragma unroll
        for (int jj = 0; jj < 4; jj++) {
            float x = fmaxf(fmaxf(acc[m][0][jj], acc[m][1][jj]),
                            fmaxf(acc[m][2][jj], acc[m][3][jj]));
#pragma unroll
            for (int o = 1; o < 16; o <<= 1) x = fmaxf(x, __shfl_xor(x, o, 64));
            if (cl == 0) wred[wc][wr * 64 + m * 16 + rg * 4 + jj] = x;
        }
    __syncthreads();
    // per-row sum of exp(v - rowmax)
#pragma unroll
    for (int m = 0; m < 4; m++)
#pragma unroll
        for (int jj = 0; jj < 4; jj++) {
            int rloc = wr * 64 + m * 16 + rg * 4 + jj;
            float mr = fmaxf(wred[0][rloc], wred[1][rloc]);
            float sse = __expf(acc[m][0][jj] - mr) + __expf(acc[m][1][jj] - mr) +
                        __expf(acc[m][2][jj] - mr) + __expf(acc[m][3][jj] - mr);
#pragma unroll
            for (int o = 1; o < 16; o <<= 1) sse += __shfl_xor(sse, o, 64);
            if (cl == 0) wsum[wc][rloc] = sse;
        }
    // raw store (masked+scaled)
#pragma unroll
    for (int m = 0; m < 4; m++)
#pragma unroll
        for (int n = 0; n < 4; n++) {
            int col = c0 + wc * 64 + n * 16 + cl;
#pragma unroll
            for (int jj = 0; jj < 4; jj++) {
                int row = r0 + wr * 64 + m * 16 + rg * 4 + jj;
                raw[(size_t)row * S + col] = acc[m][n][jj];
            }
        }
    __syncthreads();
    if (t < 128) {
        float mr = fmaxf(wred[0][t], wred[1][t]);
        pm[(size_t)bj * S + r0 + t] = mr;
        pl[(size_t)bj * S + r0 + t] = wsum[0][t] + wsum[1][t];
    }
}

// ---------------- combine tile partials -> per-row M, 1/l ----------------
__global__ __launch_bounds__(256) void k_combine(const float* __restrict__ pm,
                                                 const float* __restrict__ pl,
                                                 float* __restrict__ M,
                                                 float* __restrict__ Li) {
    int row = blockIdx.x * 256 + threadIdx.x;
    int nt = (row >> 7) + 1;
    float m = -3e38f;
    for (int j = 0; j < nt; j++) m = fmaxf(m, pm[(size_t)j * S + row]);
    float l = 0.f;
    for (int j = 0; j < nt; j++) l += pl[(size_t)j * S + row] * __expf(pm[(size_t)j * S + row] - m);
    M[row] = m;
    Li[row] = 1.0f / l;
}

// ---------------- fused normalize + final attn write + PV ----------------
__global__ __launch_bounds__(512) void k_pvnorm(const float* __restrict__ raw,
                                                const short* __restrict__ Vt,
                                                const float* __restrict__ M,
                                                const float* __restrict__ Li,
                                                float* __restrict__ attn,
                                                float* __restrict__ out) {
    int idx = blockIdx.x;
    int panel = 63 - (idx & 63);   // heavy panels dispatch first
    int rest = idx >> 6;           // 0..7
    int bn = rest & 1;
    int kz = rest >> 1;            // 0..KZ-1
    int r0 = panel * 128;
    int t = threadIdx.x;
    int nst = (panel + 1) * 4;
    int per = (nst + KZ - 1) / KZ;
    int st0 = kz * per, st1 = min(nst, st0 + per);
    if (st0 >= st1) return;
    __shared__ __align__(16) short As[128 * 32];
    __shared__ __align__(16) short Bs[256 * 32];
    __shared__ float Ml[128], Ll[128];
    if (t < 128) { Ml[t] = M[r0 + t]; Ll[t] = Li[r0 + t]; }
    int lane = t & 63, w = t >> 6, wr = w >> 2, wc = w & 3;
    f32x4 acc[4][4];
#pragma unroll
    for (int m = 0; m < 4; m++)
#pragma unroll
        for (int n = 0; n < 4; n++)
#pragma unroll
            for (int j = 0; j < 4; j++) acc[m][n][j] = 0.0f;

    const short* vbase = Vt + (size_t)(bn * 256) * S;
    for (int st = st0; st < st1; ++st) {
        int kk = st * 32;
        __syncthreads();
        // stage P: read raw, normalize, write final attn (bn==0 only), bf16 -> LDS
#pragma unroll
        for (int j = 0; j < 2; j++) {
            int c = t + j * 512;
            int r = c >> 3, kc = (c & 7) * 4;
            float4 v = *reinterpret_cast<const float4*>(&raw[(size_t)(r0 + r) * S + kk + kc]);
            float mlr = Ml[r], llr = Ll[r];
            float4 p;
            p.x = __expf(v.x - mlr) * llr;
            p.y = __expf(v.y - mlr) * llr;
            p.z = __expf(v.z - mlr) * llr;
            p.w = __expf(v.w - mlr) * llr;
            if (bn == 0)
                *reinterpret_cast<float4*>(&attn[(size_t)(r0 + r) * S + kk + kc]) = p;
            *reinterpret_cast<uint2*>(&As[r * 32 + kc]) = pack4(p);
        }
        // stage V (256 rows of Vt starting at bn*256)
        stage_g2l(vbase + kk, S, Bs, t);
        __syncthreads();
        mfma_tile(As, Bs, acc, wr, wc, lane);
    }
    int rg = lane >> 4, cl = lane & 15;
#pragma unroll
    for (int m = 0; m < 4; m++)
#pragma unroll
        for (int n = 0; n < 4; n++) {
            int col = bn * 256 + wc * 64 + n * 16 + cl;
#pragma unroll
            for (int jj = 0; jj < 4; jj++) {
                int row = r0 + wr * 64 + m * 16 + rg * 4 + jj;
                atomicAdd(&out[(size_t)row * D + col], acc[m][n][jj]);
            }
        }
}

extern "C" void kernel_launch(void* const* d_in, const int* in_sizes, int n_in,
                              void* d_out, int out_size, void* d_ws, size_t ws_size,
                              hipStream_t stream) {
    const float* x  = (const float*)d_in[0];
    const float* Wq = (const float*)d_in[1];
    const float* bq = (const float*)d_in[2];
    const float* Wk = (const float*)d_in[3];
    const float* bk = (const float*)d_in[4];
    const float* Wv = (const float*)d_in[5];
    const float* bv = (const float*)d_in[6];
    float* out  = (float*)d_out;
    float* attn = out + (size_t)S * D;

    short* xb  = (short*)d_ws;                 // S*D bf16
    short* Wb  = xb + (size_t)S * D;           // 3*D*D bf16
    short* QKV = Wb + (size_t)3 * D * D;       // 3*S*D bf16
    short* Vt  = QKV + (size_t)3 * S * D;      // D*S bf16
    float* raw = (float*)(Vt + (size_t)S * D); // S*S fp32 (lower tiles only touched)
    float* pm  = raw + (size_t)S * S;          // [64][S]
    float* pl  = pm + (size_t)64 * S;          // [64][S]
    float* M   = pl + (size_t)64 * S;          // [S]
    float* Li  = M + S;                        // [S]

    const short* Qb = QKV;
    const short* Kb = QKV + (size_t)S * D;
    const short* Vb = QKV + (size_t)2 * S * D;

    {
        size_t total4 = (size_t)S * D / 4 + (size_t)3 * D * D / 4;
        k_convert<<<dim3((unsigned)(total4 / 256)), 256, 0, stream>>>(x, Wq, Wk, Wv, xb, Wb);
    }
    k_qkv<<<dim3(S / 128, D / 128, 3), 256, 0, stream>>>(xb, Wb, bq, bk, bv, QKV);
    k_transpose<<<dim3(S / 64, D / 64), 256, 0, stream>>>(Vb, Vt);
    k_scores<<<dim3(S / 128, S / 128), 256, 0, stream>>>(Qb, Kb, raw, attn, pm, pl);
    k_combine<<<dim3(S / 256), 256, 0, stream>>>(pm, pl, M, Li);
    hipMemsetAsync(d_out, 0, (size_t)S * D * sizeof(float), stream);
    k_pvnorm<<<dim3(2 * 64 * KZ), 512, 0, stream>>>(raw, Vt, M, Li, attn, out);
}

// Round 5
// 573.852 us; speedup vs baseline: 1.0251x; 1.0251x over previous
//
#include <hip/hip_runtime.h>
#include <hip/hip_bf16.h>
#include <stdint.h>

#define S 8192
#define D 512
#define SCALE 0.044194173824159216f  // 1/sqrt(512)
#define CH 32                        // k-steps (32 cols each) per PV block

typedef __attribute__((ext_vector_type(8))) short short8;
typedef __attribute__((ext_vector_type(4))) float f32x4;

__device__ inline unsigned short f32_to_bf16(float f) {
    union { float f; uint32_t u; } v; v.f = f;
    uint32_t u = v.u;
    return (unsigned short)((u + 0x7FFFu + ((u >> 16) & 1u)) >> 16);
}
__device__ inline float bf2f(unsigned short u) {
    union { float f; uint32_t v; } x; x.v = (uint32_t)u << 16; return x.f;
}
__device__ inline uint2 pack4(float4 v) {
    uint2 p;
    p.x = (uint32_t)f32_to_bf16(v.x) | ((uint32_t)f32_to_bf16(v.y) << 16);
    p.y = (uint32_t)f32_to_bf16(v.z) | ((uint32_t)f32_to_bf16(v.w) << 16);
    return p;
}

__device__ inline void gload16(const void* g, void* l) {
    __builtin_amdgcn_global_load_lds(
        (const __attribute__((address_space(1))) unsigned int*)g,
        (__attribute__((address_space(3))) unsigned int*)l, 16, 0, 0);
}

// stage 128x64 bf16 tile from row-major src (ld shorts) into linear LDS [128][64]
__device__ inline void stage128x64(const short* __restrict__ src, int ld,
                                   short* dst, int w, int lane) {
#pragma unroll
    for (int j = 0; j < 4; j++) {
        int c = (w * 4 + j) * 64 + lane;   // 16B-chunk id, 0..1023
        int row = c >> 3, q = c & 7;
        gload16(src + (size_t)row * ld + q * 8, dst + (size_t)(w * 4 + j) * 512);
    }
}

// one BK=64 step of 128x128 MFMA (4 waves, wave tile 64x64)
__device__ inline void mfma_step64(const short* As, const short* Bs,
                                   f32x4 acc[4][4], int wr, int wc, int lane) {
    int rl = lane & 15, kg = lane >> 4;
#pragma unroll
    for (int kk0 = 0; kk0 < 64; kk0 += 32) {
        short8 a[4], b[4];
#pragma unroll
        for (int m = 0; m < 4; m++)
            a[m] = *reinterpret_cast<const short8*>(&As[(wr * 64 + m * 16 + rl) * 64 + kk0 + kg * 8]);
#pragma unroll
        for (int n = 0; n < 4; n++)
            b[n] = *reinterpret_cast<const short8*>(&Bs[(wc * 64 + n * 16 + rl) * 64 + kk0 + kg * 8]);
#pragma unroll
        for (int m = 0; m < 4; m++)
#pragma unroll
            for (int n = 0; n < 4; n++)
                acc[m][n] = __builtin_amdgcn_mfma_f32_16x16x32_bf16(a[m], b[n], acc[m][n], 0, 0, 0);
    }
}

// ---------------- convert fp32 inputs to bf16 ----------------
__global__ __launch_bounds__(256) void k_convert(
    const float* __restrict__ x, const float* __restrict__ Wq,
    const float* __restrict__ Wk, const float* __restrict__ Wv,
    short* __restrict__ xb, short* __restrict__ Wb) {
    size_t i4 = (size_t)blockIdx.x * 256 + threadIdx.x;
    const size_t XN4 = (size_t)S * D / 4;
    if (i4 < XN4) {
        float4 v = reinterpret_cast<const float4*>(x)[i4];
        reinterpret_cast<uint2*>(xb)[i4] = pack4(v);
    } else {
        size_t j4 = i4 - XN4;
        size_t w = j4 >> 16;
        size_t rem = j4 & 65535;
        const float* src = (w == 0) ? Wq : ((w == 1) ? Wk : Wv);
        float4 v = reinterpret_cast<const float4*>(src)[rem];
        reinterpret_cast<uint2*>(Wb)[j4] = pack4(v);
    }
}

// ---------------- QKV projection (BK=64, LDS-bounce epilogue) ----------------
__global__ __launch_bounds__(256) void k_qkv(
    const short* __restrict__ xb, const short* __restrict__ Wb,
    const float* __restrict__ bq, const float* __restrict__ bk,
    const float* __restrict__ bv, short* __restrict__ QKV) {
    __shared__ __align__(16) short smem[128 * 128];  // 32 KB
    short* As = smem;                 // [128][64]
    short* Bs = smem + 128 * 64;      // [128][64]
    int which = blockIdx.z;
    const short* W = Wb + (size_t)which * D * D;
    const float* bias = (which == 0) ? bq : ((which == 1) ? bk : bv);
    short* out = QKV + (size_t)which * S * D;
    int r0 = blockIdx.x * 128, c0 = blockIdx.y * 128;
    int t = threadIdx.x, lane = t & 63, w = t >> 6, wr = w >> 1, wc = w & 1;
    f32x4 acc[4][4];
#pragma unroll
    for (int m = 0; m < 4; m++)
#pragma unroll
        for (int n = 0; n < 4; n++)
#pragma unroll
            for (int j = 0; j < 4; j++) acc[m][n][j] = 0.0f;

    for (int kk = 0; kk < D; kk += 64) {
        __syncthreads();
        stage128x64(xb + (size_t)r0 * D + kk, D, As, w, lane);
        stage128x64(W + (size_t)c0 * D + kk, D, Bs, w, lane);
        __syncthreads();
        mfma_step64(As, Bs, acc, wr, wc, lane);
    }
    __syncthreads();
    short* Es = smem;   // [128][128] bounce, 32 KB
    int rg = lane >> 4, cl = lane & 15;
#pragma unroll
    for (int m = 0; m < 4; m++)
#pragma unroll
        for (int n = 0; n < 4; n++) {
            int cloc = wc * 64 + n * 16 + cl;
            float b = bias[c0 + cloc];
#pragma unroll
            for (int jj = 0; jj < 4; jj++) {
                int rloc = wr * 64 + m * 16 + rg * 4 + jj;
                Es[rloc * 128 + cloc] = (short)f32_to_bf16(acc[m][n][jj] + b);
            }
        }
    __syncthreads();
#pragma unroll
    for (int j = 0; j < 8; j++) {
        int c = t + j * 256;            // 0..2047 chunks, 16 per row
        int row = c >> 4, q = c & 15;
        *reinterpret_cast<uint4*>(&out[(size_t)(r0 + row) * D + c0 + q * 8]) =
            *reinterpret_cast<const uint4*>(&Es[row * 128 + q * 8]);
    }
}

// ---------------- V transpose ----------------
__global__ __launch_bounds__(256) void k_transpose(const short* __restrict__ V,
                                                   short* __restrict__ Vt) {
    __shared__ short tile[64][65];
    int r0 = blockIdx.x * 64;
    int c0 = blockIdx.y * 64;
    int t = threadIdx.x;
#pragma unroll
    for (int j = 0; j < 16; j++) {
        int idx = t + j * 256;
        int r = idx >> 6, c = idx & 63;
        tile[r][c] = V[(size_t)(r0 + r) * D + c0 + c];
    }
    __syncthreads();
#pragma unroll
    for (int j = 0; j < 16; j++) {
        int idx = t + j * 256;
        int rr = idx >> 6, cc = idx & 63;
        Vt[(size_t)(c0 + rr) * S + r0 + cc] = tile[cc][rr];
    }
}

// ---------------- scores: E = exp(mask(QK^T*scale)) bf16 + row-sum partials ----------------
__global__ __launch_bounds__(256) void k_scores(const short* __restrict__ Qb,
                                                const short* __restrict__ Kb,
                                                short* __restrict__ E,
                                                float* __restrict__ pl) {
    int bid = blockIdx.x;
    int bi = 0, bj = 0;
    { int c = 0;
      for (int p = 0; p < 64; p++) { int n = p + 1;
          if (bid < c + n) { bi = p; bj = bid - c; break; } c += n; } }
    int r0 = bi * 128, c0 = bj * 128;
    __shared__ __align__(16) short smem[128 * 128];  // 32 KB
    short* As = smem;
    short* Bs = smem + 128 * 64;
    __shared__ float wsum[2][128];
    int t = threadIdx.x, lane = t & 63, w = t >> 6, wr = w >> 1, wc = w & 1;
    f32x4 acc[4][4];
#pragma unroll
    for (int m = 0; m < 4; m++)
#pragma unroll
        for (int n = 0; n < 4; n++)
#pragma unroll
            for (int j = 0; j < 4; j++) acc[m][n][j] = 0.0f;

    for (int kk = 0; kk < D; kk += 64) {
        __syncthreads();
        stage128x64(Qb + (size_t)r0 * D + kk, D, As, w, lane);
        stage128x64(Kb + (size_t)c0 * D + kk, D, Bs, w, lane);
        __syncthreads();
        mfma_step64(As, Bs, acc, wr, wc, lane);
    }
    int rg = lane >> 4, cl = lane & 15;
    bool diag = (bi == bj);
    // e = exp(s*scale) (masked), row-sum partials
#pragma unroll
    for (int m = 0; m < 4; m++)
#pragma unroll
        for (int jj = 0; jj < 4; jj++) {
            int rloc = wr * 64 + m * 16 + rg * 4 + jj;
            float s4 = 0.f;
#pragma unroll
            for (int n = 0; n < 4; n++) {
                int cloc = wc * 64 + n * 16 + cl;
                float sv = acc[m][n][jj] * SCALE;
                float e = (diag && cloc > rloc) ? 0.0f : __expf(sv);
                acc[m][n][jj] = e;
                s4 += e;
            }
#pragma unroll
            for (int o = 1; o < 16; o <<= 1) s4 += __shfl_xor(s4, o, 64);
            if (cl == 0) wsum[wc][rloc] = s4;
        }
    __syncthreads();   // all MFMA + wsum done; safe to reuse smem
    if (t < 128) pl[(size_t)bj * S + r0 + t] = wsum[0][t] + wsum[1][t];
    short* Es = smem;  // [128][128] bounce
#pragma unroll
    for (int m = 0; m < 4; m++)
#pragma unroll
        for (int n = 0; n < 4; n++) {
            int cloc = wc * 64 + n * 16 + cl;
#pragma unroll
            for (int jj = 0; jj < 4; jj++) {
                int rloc = wr * 64 + m * 16 + rg * 4 + jj;
                Es[rloc * 128 + cloc] = (short)f32_to_bf16(acc[m][n][jj]);
            }
        }
    __syncthreads();
#pragma unroll
    for (int j = 0; j < 8; j++) {
        int c = t + j * 256;            // 0..2047 chunks, 16 per row
        int row = c >> 4, q = c & 15;
        *reinterpret_cast<uint4*>(&E[(size_t)(r0 + row) * S + c0 + q * 8]) =
            *reinterpret_cast<const uint4*>(&Es[row * 128 + q * 8]);
    }
}

// ---------------- combine: Li = 1/sum ----------------
__global__ __launch_bounds__(256) void k_combine(const float* __restrict__ pl,
                                                 float* __restrict__ Li) {
    int row = blockIdx.x * 256 + threadIdx.x;
    int nt = (row >> 7) + 1;
    float l = 0.f;
    for (int j = 0; j < nt; j++) l += pl[(size_t)j * S + row];
    Li[row] = 1.0f / l;
}

// ---------------- zero strictly-upper 128x128 tiles of attn ----------------
__global__ __launch_bounds__(256) void k_zero(float* __restrict__ attn) {
    int bid = blockIdx.x;
    int bi = 0, bj = 0;
    { int c = 0;
      for (int p = 0; p < 63; p++) { int n = 63 - p;
          if (bid < c + n) { bi = p; bj = p + 1 + (bid - c); break; } c += n; } }
    int t = threadIdx.x;
    float4 z = make_float4(0.f, 0.f, 0.f, 0.f);
#pragma unroll
    for (int j = 0; j < 16; j++) {
        int c = t + j * 256;
        int row = c >> 5, q = (c & 31) * 4;
        *reinterpret_cast<float4*>(&attn[(size_t)(bi * 128 + row) * S + bj * 128 + q]) = z;
    }
}

// ---------------- PV: out = (E @ Vt^T) * Li ; fused attn = E*Li write ----------------
__global__ __launch_bounds__(512) void k_pv(const short* __restrict__ E,
                                            const short* __restrict__ Vt,
                                            const float* __restrict__ Li,
                                            float* __restrict__ attn,
                                            float* __restrict__ out) {
    int bid = blockIdx.x;
    int bn = bid & 1, bidx = bid >> 1;
    int panel = 63, chunk = 0;
    { int c = 0;
      for (int p = 63; p >= 0; p--) {            // heavy panels first
          int nb = (p + 8) >> 3;                 // ceil((p+1)/8)
          if (bidx < c + nb) { panel = p; chunk = bidx - c; break; } c += nb; } }
    int nst = 4 * (panel + 1);
    int st0 = chunk * CH, st1 = min(nst, st0 + CH);
    int r0 = panel * 128, c0 = bn * 256;
    __shared__ __align__(16) short As[128 * 32];   // 8 KB
    __shared__ __align__(16) short Bs[256 * 32];   // 16 KB
    __shared__ float Lil[128];
    int t = threadIdx.x;
    if (t < 128) Lil[t] = Li[r0 + t];
    int lane = t & 63, w = t >> 6, wr = w >> 2, wc = w & 3;
    f32x4 acc[4][4];
#pragma unroll
    for (int m = 0; m < 4; m++)
#pragma unroll
        for (int n = 0; n < 4; n++)
#pragma unroll
            for (int j = 0; j < 4; j++) acc[m][n][j] = 0.0f;

    int arow = t >> 2, aq = t & 3;
    bool wrHalf = (bn == 0) ? (arow < 64) : (arow >= 64);

    for (int st = st0; st < st1; ++st) {
        int kk = st * 32;
        __syncthreads();
        // stage A: E 128x32 (512 chunks, 1 issue/wave)
        { int c = w * 64 + lane; int row = c >> 2, q = c & 3;
          gload16(E + (size_t)(r0 + row) * S + kk + q * 8, As + w * 512); }
        // stage B: Vt 256x32 (1024 chunks, 2 issues/wave)
#pragma unroll
        for (int j = 0; j < 2; j++) {
            int c = (w * 2 + j) * 64 + lane; int row = c >> 2, q = c & 3;
            gload16(Vt + (size_t)(c0 + row) * S + kk + q * 8, Bs + (size_t)(w * 2 + j) * 512);
        }
        // fused final-attn write (reads E from L2, independent stream)
        if (wrHalf) {
            const uint4 ev = *reinterpret_cast<const uint4*>(&E[(size_t)(r0 + arow) * S + kk + aq * 8]);
            float li = Lil[arow];
            const unsigned short* es = reinterpret_cast<const unsigned short*>(&ev);
            float4 o0, o1;
            o0.x = bf2f(es[0]) * li; o0.y = bf2f(es[1]) * li;
            o0.z = bf2f(es[2]) * li; o0.w = bf2f(es[3]) * li;
            o1.x = bf2f(es[4]) * li; o1.y = bf2f(es[5]) * li;
            o1.z = bf2f(es[6]) * li; o1.w = bf2f(es[7]) * li;
            float* ap = &attn[(size_t)(r0 + arow) * S + kk + aq * 8];
            *reinterpret_cast<float4*>(ap) = o0;
            *reinterpret_cast<float4*>(ap + 4) = o1;
        }
        __syncthreads();
        int rl = lane & 15, kg = lane >> 4;
        short8 a[4], b[4];
#pragma unroll
        for (int m = 0; m < 4; m++)
            a[m] = *reinterpret_cast<const short8*>(&As[(wr * 64 + m * 16 + rl) * 32 + kg * 8]);
#pragma unroll
        for (int n = 0; n < 4; n++)
            b[n] = *reinterpret_cast<const short8*>(&Bs[(wc * 64 + n * 16 + rl) * 32 + kg * 8]);
#pragma unroll
        for (int m = 0; m < 4; m++)
#pragma unroll
            for (int n = 0; n < 4; n++)
                acc[m][n] = __builtin_amdgcn_mfma_f32_16x16x32_bf16(a[m], b[n], acc[m][n], 0, 0, 0);
    }
    int rg = lane >> 4, cl = lane & 15;
#pragma unroll
    for (int m = 0; m < 4; m++)
#pragma unroll
        for (int n = 0; n < 4; n++) {
            int col = c0 + wc * 64 + n * 16 + cl;
#pragma unroll
            for (int jj = 0; jj < 4; jj++) {
                int rloc = wr * 64 + m * 16 + rg * 4 + jj;
                atomicAdd(&out[(size_t)(r0 + rloc) * D + col], acc[m][n][jj] * Lil[rloc]);
            }
        }
}

extern "C" void kernel_launch(void* const* d_in, const int* in_sizes, int n_in,
                              void* d_out, int out_size, void* d_ws, size_t ws_size,
                              hipStream_t stream) {
    const float* x  = (const float*)d_in[0];
    const float* Wq = (const float*)d_in[1];
    const float* bq = (const float*)d_in[2];
    const float* Wk = (const float*)d_in[3];
    const float* bk = (const float*)d_in[4];
    const float* Wv = (const float*)d_in[5];
    const float* bv = (const float*)d_in[6];
    float* out  = (float*)d_out;
    float* attn = out + (size_t)S * D;

    short* xb  = (short*)d_ws;                  // S*D
    short* Wb  = xb + (size_t)S * D;            // 3*D*D
    short* QKV = Wb + (size_t)3 * D * D;        // 3*S*D
    short* Vt  = QKV + (size_t)3 * S * D;       // S*D (Vt is [D][S])
    short* E   = Vt + (size_t)S * D;            // S*S bf16 (lower tiles only)
    float* pl  = (float*)(E + (size_t)S * S);   // [64][S]
    float* Li  = pl + (size_t)64 * S;           // [S]

    const short* Qb = QKV;
    const short* Kb = QKV + (size_t)S * D;
    const short* Vb = QKV + (size_t)2 * S * D;

    {
        size_t total4 = (size_t)S * D / 4 + (size_t)3 * D * D / 4;
        k_convert<<<dim3((unsigned)(total4 / 256)), 256, 0, stream>>>(x, Wq, Wk, Wv, xb, Wb);
    }
    k_qkv<<<dim3(S / 128, D / 128, 3), 256, 0, stream>>>(xb, Wb, bq, bk, bv, QKV);
    k_transpose<<<dim3(S / 64, D / 64), 256, 0, stream>>>(Vb, Vt);
    k_scores<<<dim3(64 * 65 / 2), 256, 0, stream>>>(Qb, Kb, E, pl);
    k_combine<<<dim3(S / 256), 256, 0, stream>>>(pl, Li);
    k_zero<<<dim3(63 * 64 / 2), 256, 0, stream>>>(attn);
    hipMemsetAsync(d_out, 0, (size_t)S * D * sizeof(float), stream);
    k_pv<<<dim3(2 * 288), 512, 0, stream>>>(E, Vt, Li, attn, out);
}

// Round 6
// 564.182 us; speedup vs baseline: 1.0426x; 1.0171x over previous
//
#include <hip/hip_runtime.h>
#include <hip/hip_bf16.h>
#include <stdint.h>

#define S 8192
#define D 512
#define SCALE 0.044194173824159216f  // 1/sqrt(512)
#define PVCH 16                      // 64-wide k-steps per PV chunk

typedef __attribute__((ext_vector_type(8))) short short8;
typedef __attribute__((ext_vector_type(4))) float f32x4;

__device__ inline unsigned short f32_to_bf16(float f) {
    union { float f; uint32_t u; } v; v.f = f;
    uint32_t u = v.u;
    return (unsigned short)((u + 0x7FFFu + ((u >> 16) & 1u)) >> 16);
}
__device__ inline float bf2f(unsigned short u) {
    union { float f; uint32_t v; } x; x.v = (uint32_t)u << 16; return x.f;
}
__device__ inline uint2 pack4(float4 v) {
    uint2 p;
    p.x = (uint32_t)f32_to_bf16(v.x) | ((uint32_t)f32_to_bf16(v.y) << 16);
    p.y = (uint32_t)f32_to_bf16(v.z) | ((uint32_t)f32_to_bf16(v.w) << 16);
    return p;
}

__device__ inline void gload16(const void* g, void* l) {
    __builtin_amdgcn_global_load_lds(
        (const __attribute__((address_space(1))) unsigned int*)g,
        (__attribute__((address_space(3))) unsigned int*)l, 16, 0, 0);
}

// stage 128x64 bf16 tile from row-major src (ld shorts) into linear LDS [128][64]
__device__ inline void stage128x64(const short* __restrict__ src, int ld,
                                   short* dst, int w, int lane) {
#pragma unroll
    for (int j = 0; j < 4; j++) {
        int c = (w * 4 + j) * 64 + lane;   // 16B-chunk id, 0..1023
        int row = c >> 3, q = c & 7;
        gload16(src + (size_t)row * ld + q * 8, dst + (size_t)(w * 4 + j) * 512);
    }
}

// one BK=64 step of 128x128 MFMA (4 waves, wave tile 64x64)
__device__ inline void mfma_step64(const short* As, const short* Bs,
                                   f32x4 acc[4][4], int wr, int wc, int lane) {
    int rl = lane & 15, kg = lane >> 4;
#pragma unroll
    for (int kk0 = 0; kk0 < 64; kk0 += 32) {
        short8 a[4], b[4];
#pragma unroll
        for (int m = 0; m < 4; m++)
            a[m] = *reinterpret_cast<const short8*>(&As[(wr * 64 + m * 16 + rl) * 64 + kk0 + kg * 8]);
#pragma unroll
        for (int n = 0; n < 4; n++)
            b[n] = *reinterpret_cast<const short8*>(&Bs[(wc * 64 + n * 16 + rl) * 64 + kk0 + kg * 8]);
#pragma unroll
        for (int m = 0; m < 4; m++)
#pragma unroll
            for (int n = 0; n < 4; n++)
                acc[m][n] = __builtin_amdgcn_mfma_f32_16x16x32_bf16(a[m], b[n], acc[m][n], 0, 0, 0);
    }
}

// ---------------- convert fp32 inputs to bf16 ----------------
__global__ __launch_bounds__(256) void k_convert(
    const float* __restrict__ x, const float* __restrict__ Wq,
    const float* __restrict__ Wk, const float* __restrict__ Wv,
    short* __restrict__ xb, short* __restrict__ Wb) {
    size_t i4 = (size_t)blockIdx.x * 256 + threadIdx.x;
    const size_t XN4 = (size_t)S * D / 4;
    if (i4 < XN4) {
        float4 v = reinterpret_cast<const float4*>(x)[i4];
        reinterpret_cast<uint2*>(xb)[i4] = pack4(v);
    } else {
        size_t j4 = i4 - XN4;
        size_t w = j4 >> 16;
        size_t rem = j4 & 65535;
        const float* src = (w == 0) ? Wq : ((w == 1) ? Wk : Wv);
        float4 v = reinterpret_cast<const float4*>(src)[rem];
        reinterpret_cast<uint2*>(Wb)[j4] = pack4(v);
    }
}

// ---------------- QKV projection (BK=64, LDS-bounce epilogue) ----------------
__global__ __launch_bounds__(256) void k_qkv(
    const short* __restrict__ xb, const short* __restrict__ Wb,
    const float* __restrict__ bq, const float* __restrict__ bk,
    const float* __restrict__ bv, short* __restrict__ QKV) {
    __shared__ __align__(16) short smem[128 * 128];  // 32 KB
    short* As = smem;                 // [128][64]
    short* Bs = smem + 128 * 64;      // [128][64]
    int which = blockIdx.z;
    const short* W = Wb + (size_t)which * D * D;
    const float* bias = (which == 0) ? bq : ((which == 1) ? bk : bv);
    short* out = QKV + (size_t)which * S * D;
    int r0 = blockIdx.x * 128, c0 = blockIdx.y * 128;
    int t = threadIdx.x, lane = t & 63, w = t >> 6, wr = w >> 1, wc = w & 1;
    f32x4 acc[4][4];
#pragma unroll
    for (int m = 0; m < 4; m++)
#pragma unroll
        for (int n = 0; n < 4; n++)
#pragma unroll
            for (int j = 0; j < 4; j++) acc[m][n][j] = 0.0f;

    for (int kk = 0; kk < D; kk += 64) {
        __syncthreads();
        stage128x64(xb + (size_t)r0 * D + kk, D, As, w, lane);
        stage128x64(W + (size_t)c0 * D + kk, D, Bs, w, lane);
        __syncthreads();
        mfma_step64(As, Bs, acc, wr, wc, lane);
    }
    __syncthreads();
    short* Es = smem;   // [128][128] bounce, 32 KB
    int rg = lane >> 4, cl = lane & 15;
#pragma unroll
    for (int m = 0; m < 4; m++)
#pragma unroll
        for (int n = 0; n < 4; n++) {
            int cloc = wc * 64 + n * 16 + cl;
            float b = bias[c0 + cloc];
#pragma unroll
            for (int jj = 0; jj < 4; jj++) {
                int rloc = wr * 64 + m * 16 + rg * 4 + jj;
                Es[rloc * 128 + cloc] = (short)f32_to_bf16(acc[m][n][jj] + b);
            }
        }
    __syncthreads();
#pragma unroll
    for (int j = 0; j < 8; j++) {
        int c = t + j * 256;            // 0..2047 chunks, 16 per row
        int row = c >> 4, q = c & 15;
        *reinterpret_cast<uint4*>(&out[(size_t)(r0 + row) * D + c0 + q * 8]) =
            *reinterpret_cast<const uint4*>(&Es[row * 128 + q * 8]);
    }
}

// ---------------- V transpose ----------------
__global__ __launch_bounds__(256) void k_transpose(const short* __restrict__ V,
                                                   short* __restrict__ Vt) {
    __shared__ short tile[64][65];
    int r0 = blockIdx.x * 64;
    int c0 = blockIdx.y * 64;
    int t = threadIdx.x;
#pragma unroll
    for (int j = 0; j < 16; j++) {
        int idx = t + j * 256;
        int r = idx >> 6, c = idx & 63;
        tile[r][c] = V[(size_t)(r0 + r) * D + c0 + c];
    }
    __syncthreads();
#pragma unroll
    for (int j = 0; j < 16; j++) {
        int idx = t + j * 256;
        int rr = idx >> 6, cc = idx & 63;
        Vt[(size_t)(c0 + rr) * S + r0 + cc] = tile[cc][rr];
    }
}

// ---------------- scores: E = exp(mask(QK^T*scale)) bf16 + row-sum partials ----------------
__global__ __launch_bounds__(256) void k_scores(const short* __restrict__ Qb,
                                                const short* __restrict__ Kb,
                                                short* __restrict__ E,
                                                float* __restrict__ pl) {
    int bid = blockIdx.x;
    int bi = 0, bj = 0;
    { int c = 0;
      for (int p = 0; p < 64; p++) { int n = p + 1;
          if (bid < c + n) { bi = p; bj = bid - c; break; } c += n; } }
    int r0 = bi * 128, c0 = bj * 128;
    __shared__ __align__(16) short smem[128 * 128];  // 32 KB
    short* As = smem;
    short* Bs = smem + 128 * 64;
    __shared__ float wsum[2][128];
    int t = threadIdx.x, lane = t & 63, w = t >> 6, wr = w >> 1, wc = w & 1;
    f32x4 acc[4][4];
#pragma unroll
    for (int m = 0; m < 4; m++)
#pragma unroll
        for (int n = 0; n < 4; n++)
#pragma unroll
            for (int j = 0; j < 4; j++) acc[m][n][j] = 0.0f;

    for (int kk = 0; kk < D; kk += 64) {
        __syncthreads();
        stage128x64(Qb + (size_t)r0 * D + kk, D, As, w, lane);
        stage128x64(Kb + (size_t)c0 * D + kk, D, Bs, w, lane);
        __syncthreads();
        mfma_step64(As, Bs, acc, wr, wc, lane);
    }
    int rg = lane >> 4, cl = lane & 15;
    bool diag = (bi == bj);
    // e = exp(s*scale) (masked), row-sum partials
#pragma unroll
    for (int m = 0; m < 4; m++)
#pragma unroll
        for (int jj = 0; jj < 4; jj++) {
            int rloc = wr * 64 + m * 16 + rg * 4 + jj;
            float s4 = 0.f;
#pragma unroll
            for (int n = 0; n < 4; n++) {
                int cloc = wc * 64 + n * 16 + cl;
                float sv = acc[m][n][jj] * SCALE;
                float e = (diag && cloc > rloc) ? 0.0f : __expf(sv);
                acc[m][n][jj] = e;
                s4 += e;
            }
#pragma unroll
            for (int o = 1; o < 16; o <<= 1) s4 += __shfl_xor(s4, o, 64);
            if (cl == 0) wsum[wc][rloc] = s4;
        }
    __syncthreads();   // all MFMA + wsum done; safe to reuse smem
    if (t < 128) pl[(size_t)bj * S + r0 + t] = wsum[0][t] + wsum[1][t];
    short* Es = smem;  // [128][128] bounce
#pragma unroll
    for (int m = 0; m < 4; m++)
#pragma unroll
        for (int n = 0; n < 4; n++) {
            int cloc = wc * 64 + n * 16 + cl;
#pragma unroll
            for (int jj = 0; jj < 4; jj++) {
                int rloc = wr * 64 + m * 16 + rg * 4 + jj;
                Es[rloc * 128 + cloc] = (short)f32_to_bf16(acc[m][n][jj]);
            }
        }
    __syncthreads();
#pragma unroll
    for (int j = 0; j < 8; j++) {
        int c = t + j * 256;            // 0..2047 chunks, 16 per row
        int row = c >> 4, q = c & 15;
        *reinterpret_cast<uint4*>(&E[(size_t)(r0 + row) * S + c0 + q * 8]) =
            *reinterpret_cast<const uint4*>(&Es[row * 128 + q * 8]);
    }
}

// ---------------- combine: Li = 1/sum ----------------
__global__ __launch_bounds__(256) void k_combine(const float* __restrict__ pl,
                                                 float* __restrict__ Li) {
    int row = blockIdx.x * 256 + threadIdx.x;
    int nt = (row >> 7) + 1;
    float l = 0.f;
    for (int j = 0; j < nt; j++) l += pl[(size_t)j * S + row];
    Li[row] = 1.0f / l;
}

// ---------------- attn output: upper tiles = 0, lower/diag = E * Li (fp32) ----------------
__global__ __launch_bounds__(256) void k_attn(const short* __restrict__ E,
                                              const float* __restrict__ Li,
                                              float* __restrict__ attn) {
    int bj = blockIdx.x, bi = blockIdx.y;
    int r0 = bi * 128, c0 = bj * 128;
    int t = threadIdx.x;
    if (bj > bi) {
        float4 z = make_float4(0.f, 0.f, 0.f, 0.f);
#pragma unroll
        for (int j = 0; j < 16; j++) {
            int c = t + j * 256;
            int row = c >> 5, q = (c & 31) * 4;
            *reinterpret_cast<float4*>(&attn[(size_t)(r0 + row) * S + c0 + q]) = z;
        }
        return;
    }
    __shared__ float Lil[128];
    if (t < 128) Lil[t] = Li[r0 + t];
    __syncthreads();
#pragma unroll
    for (int j = 0; j < 8; j++) {
        int c = t + j * 256;            // 2048 chunks of 8 elems
        int row = c >> 4, q = c & 15;
        uint4 ev = *reinterpret_cast<const uint4*>(&E[(size_t)(r0 + row) * S + c0 + q * 8]);
        float li = Lil[row];
        const unsigned short* es = reinterpret_cast<const unsigned short*>(&ev);
        float4 o0, o1;
        o0.x = bf2f(es[0]) * li; o0.y = bf2f(es[1]) * li;
        o0.z = bf2f(es[2]) * li; o0.w = bf2f(es[3]) * li;
        o1.x = bf2f(es[4]) * li; o1.y = bf2f(es[5]) * li;
        o1.z = bf2f(es[6]) * li; o1.w = bf2f(es[7]) * li;
        float* ap = &attn[(size_t)(r0 + row) * S + c0 + q * 8];
        *reinterpret_cast<float4*>(ap) = o0;
        *reinterpret_cast<float4*>(ap + 4) = o1;
    }
}

// ---------------- PV: out = (E @ Vt^T) * Li — pure GEMM, k-chunked, atomics ----------------
__global__ __launch_bounds__(256) void k_pv(const short* __restrict__ E,
                                            const short* __restrict__ Vt,
                                            const float* __restrict__ Li,
                                            float* __restrict__ out) {
    int bid = blockIdx.x;
    int bn = bid & 3;                 // 4 col-tiles of 128
    int bidx = bid >> 2;
    int panel = 63, chunk = 0;
    { int c = 0;
      for (int p = 63; p >= 0; p--) {            // heavy panels first
          int nb = (p + 8) >> 3;                 // ceil(2(p+1)/PVCH), PVCH=16
          if (bidx < c + nb) { panel = p; chunk = bidx - c; break; } c += nb; } }
    int nst = 2 * (panel + 1);                   // BK=64 steps
    int st0 = chunk * PVCH, st1 = min(nst, st0 + PVCH);
    int r0 = panel * 128, c0 = bn * 128;
    __shared__ __align__(16) short smem[128 * 128];  // 32 KB
    short* As = smem;
    short* Bs = smem + 128 * 64;
    __shared__ float Lil[128];
    int t = threadIdx.x;
    if (t < 128) Lil[t] = Li[r0 + t];
    int lane = t & 63, w = t >> 6, wr = w >> 1, wc = w & 1;
    f32x4 acc[4][4];
#pragma unroll
    for (int m = 0; m < 4; m++)
#pragma unroll
        for (int n = 0; n < 4; n++)
#pragma unroll
            for (int j = 0; j < 4; j++) acc[m][n][j] = 0.0f;

    for (int st = st0; st < st1; ++st) {
        int kk = st * 64;
        __syncthreads();
        stage128x64(E + (size_t)r0 * S + kk, S, As, w, lane);
        stage128x64(Vt + (size_t)c0 * S + kk, S, Bs, w, lane);
        __syncthreads();
        mfma_step64(As, Bs, acc, wr, wc, lane);
    }
    int rg = lane >> 4, cl = lane & 15;
#pragma unroll
    for (int m = 0; m < 4; m++)
#pragma unroll
        for (int n = 0; n < 4; n++) {
            int col = c0 + wc * 64 + n * 16 + cl;
#pragma unroll
            for (int jj = 0; jj < 4; jj++) {
                int rloc = wr * 64 + m * 16 + rg * 4 + jj;
                atomicAdd(&out[(size_t)(r0 + rloc) * D + col], acc[m][n][jj] * Lil[rloc]);
            }
        }
}

extern "C" void kernel_launch(void* const* d_in, const int* in_sizes, int n_in,
                              void* d_out, int out_size, void* d_ws, size_t ws_size,
                              hipStream_t stream) {
    const float* x  = (const float*)d_in[0];
    const float* Wq = (const float*)d_in[1];
    const float* bq = (const float*)d_in[2];
    const float* Wk = (const float*)d_in[3];
    const float* bk = (const float*)d_in[4];
    const float* Wv = (const float*)d_in[5];
    const float* bv = (const float*)d_in[6];
    float* out  = (float*)d_out;
    float* attn = out + (size_t)S * D;

    short* xb  = (short*)d_ws;                  // S*D
    short* Wb  = xb + (size_t)S * D;            // 3*D*D
    short* QKV = Wb + (size_t)3 * D * D;        // 3*S*D
    short* Vt  = QKV + (size_t)3 * S * D;       // S*D (Vt is [D][S])
    short* E   = Vt + (size_t)S * D;            // S*S bf16 (lower tiles only)
    float* pl  = (float*)(E + (size_t)S * S);   // [64][S]
    float* Li  = pl + (size_t)64 * S;           // [S]

    const short* Qb = QKV;
    const short* Kb = QKV + (size_t)S * D;
    const short* Vb = QKV + (size_t)2 * S * D;

    {
        size_t total4 = (size_t)S * D / 4 + (size_t)3 * D * D / 4;
        k_convert<<<dim3((unsigned)(total4 / 256)), 256, 0, stream>>>(x, Wq, Wk, Wv, xb, Wb);
    }
    k_qkv<<<dim3(S / 128, D / 128, 3), 256, 0, stream>>>(xb, Wb, bq, bk, bv, QKV);
    k_transpose<<<dim3(S / 64, D / 64), 256, 0, stream>>>(Vb, Vt);
    k_scores<<<dim3(64 * 65 / 2), 256, 0, stream>>>(Qb, Kb, E, pl);
    k_combine<<<dim3(S / 256), 256, 0, stream>>>(pl, Li);
    k_attn<<<dim3(64, 64), 256, 0, stream>>>(E, Li, attn);
    hipMemsetAsync(d_out, 0, (size_t)S * D * sizeof(float), stream);
    k_pv<<<dim3(288 * 4), 256, 0, stream>>>(E, Vt, Li, out);
}